// Round 4
// baseline (312.029 us; speedup 1.0000x reference)
//
#include <hip/hip_runtime.h>
#include <math.h>

// CapsLayer dynamic routing, MI355X fp32.
// x: [64, 2048, 8]  W: [2048, 32, 8, 16]  out: [64, 32, 16]
// Never materialize u_hat (256 MB); recompute per routing pass.
// R6: depth-1 software pipeline for W. R5 fixed the spill (VGPR 36, FETCH
// 35 MB) but route_pass sits at 47.6us vs ~9.5us VALU floor, VALUBusy 18%:
// with unroll 1 each iteration serializes [8 W loads -> vmcnt wait -> FMA].
// Ping-pong register tiles wr_a/wr_b: issue next tile's loads, compute on
// current. ~70 VGPR live (<128 cap of (256,4)). MODE1 barrier becomes
// lgkmcnt-only (raw s_barrier): __syncthreads drains vmcnt(0) which would
// kill the in-flight prefetch; the barrier only protects wsum (LDS).
// Kept: unroll 1 on outer loop (spill guard), 2048-block grid, aws
// elimination via dot linearity, parallel 512-block reduce_squash.

#define B_TOT 64
#define I_TOT 2048
#define D_IN  8
#define NC    32
#define EV    16
#define OD    (NC*EV)      // 512 outputs per b
#define BC    8            // batch rows per block
#define NBC   (B_TOT/BC)   // 8 b-chunks
#define ICH   8            // i's per block
#define NIC   (I_TOT/ICH)  // 256 i-chunks

__device__ __forceinline__ void fma4(float4& acc, float a, const float4& w) {
    acc.x = fmaf(a, w.x, acc.x);
    acc.y = fmaf(a, w.y, acc.y);
    acc.z = fmaf(a, w.z, acc.z);
    acc.w = fmaf(a, w.w, acc.w);
}

// MODE 0: c uniform (iter 0)              -> P partials
// MODE 1: c = softmax_n(u . vin)          -> P partials
//         (iter 2 uses vin = v0+v1: dot is linear, so no logit carry needed)
template <int MODE>
__global__ __launch_bounds__(256, 4)
void route_pass(const float* __restrict__ x, const float* __restrict__ W,
                float* __restrict__ P, const float* __restrict__ vin)
{
    __shared__ __align__(16) float xl[BC * ICH * D_IN];   // 2 KB
    __shared__ float wsum[2][4][BC];                      // 256 B (double-buffered)

    const int t  = threadIdx.x;
    // XCD swizzle: blk%8 == ic%8 (NIC = 256 ≡ 0 mod 8), so the 8 bc-siblings
    // of an ic (which share W[i0..i0+7]) land on the same XCD's L2.
    // Per-XCD W working set = 2 MB < 4 MB L2.
    const int ic = blockIdx.x & (NIC - 1);   // 0..255
    const int bc = blockIdx.x >> 8;          // 0..7
    const int b0 = bc * BC;
    const int i0 = ic * ICH;
    const int eq = t & 3;          // e quarter (4 e's)
    const int bh = (t >> 2) & 1;   // b half (4 b's each)
    const int n  = t >> 3;         // capsule 0..31
    const int w  = t >> 6;         // wave 0..3

    const float* Wt = &W[(size_t)i0 * 4096 + n * 128 + eq * 4];

    // ---- prologue: issue tile-0 W loads first (longest pole) ----
    float4 wr_a[8], wr_b[8];
    {
        const float4* wp = (const float4*)Wt;
        #pragma unroll
        for (int d = 0; d < 8; ++d) wr_a[d] = wp[d * 4];
    }

    // ---- stage x[b0..b0+7][i0..i0+7][0..7] once (2 KB) ----
    if (t < 128) {
        const int row = t >> 4, f = (t & 15) * 4;
        *(float4*)&xl[row * (ICH * D_IN) + f] =
            *(const float4*)&x[((size_t)(b0 + row) * I_TOT + i0) * D_IN + f];
    }

    // ---- v fragments in registers (loaded once; L2-hot, tiny) ----
    float4 vr[4];
    if (MODE == 1) {
        #pragma unroll
        for (int q = 0; q < 4; ++q)
            vr[q] = *(const float4*)&vin[(size_t)(b0 + bh * 4 + q) * OD + n * EV + eq * 4];
    }
    __syncthreads();

    float4 sacc[4];
    #pragma unroll
    for (int q = 0; q < 4; ++q) sacc[q] = make_float4(0.f, 0.f, 0.f, 0.f);

    // one half-step: compute with tile wr at index ii
    auto body = [&](int ii, const float4 (&wr)[8]) {
        // ---- u[bl][eq*4..+3] for 4 batch rows ----
        float4 u[4];
        #pragma unroll
        for (int q = 0; q < 4; ++q) {
            const int bl = bh * 4 + q;
            float4 xa = *(float4*)&xl[bl * (ICH * D_IN) + ii * 8];
            float4 xb = *(float4*)&xl[bl * (ICH * D_IN) + ii * 8 + 4];
            float4 uu = make_float4(0.f, 0.f, 0.f, 0.f);
            fma4(uu, xa.x, wr[0]); fma4(uu, xa.y, wr[1]);
            fma4(uu, xa.z, wr[2]); fma4(uu, xa.w, wr[3]);
            fma4(uu, xb.x, wr[4]); fma4(uu, xb.y, wr[5]);
            fma4(uu, xb.z, wr[6]); fma4(uu, xb.w, wr[7]);
            u[q] = uu;
        }

        if (MODE == 0) {
            #pragma unroll
            for (int q = 0; q < 4; ++q) {
                sacc[q].x += u[q].x; sacc[q].y += u[q].y;
                sacc[q].z += u[q].z; sacc[q].w += u[q].w;
            }
            // no barrier: xl is read-only, no LDS communication
        } else {
            // ---- a[bl] = dot(u, v) over e: 4 in-thread + shfl over eq bits ----
            float a[4];
            #pragma unroll
            for (int q = 0; q < 4; ++q) {
                float ap = u[q].x * vr[q].x + u[q].y * vr[q].y
                         + u[q].z * vr[q].z + u[q].w * vr[q].w;
                ap += __shfl_xor(ap, 1, 64);
                ap += __shfl_xor(ap, 2, 64);
                a[q] = ap;
            }
            // ---- softmax over n: exp, in-wave partial over this wave's 8 n's ----
            float e[4], p[4];
            #pragma unroll
            for (int q = 0; q < 4; ++q) {
                e[q] = __expf(a[q]);
                float pp = e[q];
                pp += __shfl_xor(pp, 8, 64);
                pp += __shfl_xor(pp, 16, 64);
                pp += __shfl_xor(pp, 32, 64);
                p[q] = pp;       // sum over n in this wave, for bl = bh*4+q
            }
            if (eq == 0) {
                #pragma unroll
                for (int q = 0; q < 4; ++q)
                    wsum[ii & 1][w][bh * 4 + q] = p[q];
            }
            // lgkm-only barrier: do NOT drain vmcnt (prefetch stays in flight).
            // wsum visibility only needs ds_write completion + barrier.
            asm volatile("s_waitcnt lgkmcnt(0)\n\ts_barrier" ::: "memory");
            #pragma unroll
            for (int q = 0; q < 4; ++q) {
                const int bl = bh * 4 + q;
                float s = wsum[ii & 1][0][bl] + wsum[ii & 1][1][bl]
                        + wsum[ii & 1][2][bl] + wsum[ii & 1][3][bl];
                float c = e[q] / s;
                fma4(sacc[q], c, u[q]);
            }
        }
    };

    // ---- main loop: depth-1 ping-pong pipeline, no full unroll (spill!) ----
    #pragma unroll 1
    for (int ii = 0; ii < ICH; ii += 2) {
        {   // prefetch tile ii+1 -> wr_b, compute tile ii from wr_a
            const float4* wp = (const float4*)&Wt[(ii + 1) * 4096];
            #pragma unroll
            for (int d = 0; d < 8; ++d) wr_b[d] = wp[d * 4];
        }
        body(ii, wr_a);
        {   // prefetch tile ii+2 -> wr_a (clamped; last is redundant reload)
            const int nxt = (ii + 2 < ICH) ? (ii + 2) : (ICH - 1);
            const float4* wp = (const float4*)&Wt[nxt * 4096];
            #pragma unroll
            for (int d = 0; d < 8; ++d) wr_a[d] = wp[d * 4];
        }
        body(ii + 1, wr_b);
    }

    // ---- write partials: P[ic][b][o] (64B-coalesced, full 128B lines/wave) ----
    #pragma unroll
    for (int q = 0; q < 4; ++q)
        *(float4*)&P[((size_t)ic * B_TOT + b0 + bh * 4 + q) * OD + n * EV + eq * 4] = sacc[q];
}

// Reduce partials over 256 i-chunks, then squash per (b, n).
// Grid: 64 b x 8 output-slices = 512 blocks (2/CU, all CUs busy).
// Block: 256 threads = 64 outputs x 4 ic-quarters; LDS combine; 64 survivors
// do the squash (norm over the 16-lane e-group) and store.
// If addsrc != null, out = squash(...) + addsrc  (used to produce v0+v1).
__global__ __launch_bounds__(256, 4)
void reduce_squash(const float* __restrict__ P, float* __restrict__ dst,
                   const float* __restrict__ addsrc, float pre)
{
    __shared__ float red[256];
    const int b   = blockIdx.x >> 3;
    const int oq  = blockIdx.x & 7;
    const int t   = threadIdx.x;
    const int o   = oq * 64 + (t & 63);
    const int icq = t >> 6;                       // 0..3
    const size_t stride = (size_t)B_TOT * OD;     // per-ic stride in floats

    float s = 0.f;
    size_t base = ((size_t)(icq * 64) * B_TOT + b) * OD + o;
    #pragma unroll 8
    for (int k = 0; k < 64; ++k) s += P[base + (size_t)k * stride];
    red[t] = s;
    __syncthreads();

    if (t < 64) {
        float v = red[t] + red[t + 64] + red[t + 128] + red[t + 192];
        v *= pre;
        // squared norm over e (16 consecutive lanes = one capsule)
        float q2 = v * v;
        q2 += __shfl_xor(q2, 1, 64);
        q2 += __shfl_xor(q2, 2, 64);
        q2 += __shfl_xor(q2, 4, 64);
        q2 += __shfl_xor(q2, 8, 64);
        float sc = q2 / ((1.0f + q2) * sqrtf(q2));
        float outv = v * sc;
        if (addsrc) outv += addsrc[b * OD + o];
        dst[b * OD + o] = outv;
    }
}

extern "C" void kernel_launch(void* const* d_in, const int* in_sizes, int n_in,
                              void* d_out, int out_size, void* d_ws, size_t ws_size,
                              hipStream_t stream) {
    const float* x = (const float*)d_in[0];
    const float* W = (const float*)d_in[1];
    float* out = (float*)d_out;

    char* ws = (char*)d_ws;
    float* P  = (float*)ws;                               // NIC*64*512*4 = 32 MB
    float* v0 = (float*)(ws + (size_t)32 * 1024 * 1024);  // 64*512*4 = 128 KB
    float* vs = v0 + B_TOT * OD;                          // v0 + v1

    dim3 rg(NBC * NIC), rb(256);   // 2048 blocks; ~70 VGPR -> >=5 waves/SIMD ok
    dim3 sg(B_TOT * 8), sb(256);   // 512 blocks

    // iter 0: uniform c = 1/32
    route_pass<0><<<rg, rb, 0, stream>>>(x, W, P, nullptr);
    reduce_squash<<<sg, sb, 0, stream>>>(P, v0, nullptr, 1.0f / 32.0f);
    // iter 1: c = softmax(u.v0)
    route_pass<1><<<rg, rb, 0, stream>>>(x, W, P, v0);
    // vs = v0 + v1  (iter-2 logits: u.v0 + u.v1 = u.(v0+v1))
    reduce_squash<<<sg, sb, 0, stream>>>(P, vs, v0, 1.0f);
    // iter 2: c = softmax(u.(v0+v1)); final
    route_pass<1><<<rg, rb, 0, stream>>>(x, W, P, vs);
    reduce_squash<<<sg, sb, 0, stream>>>(P, out, nullptr, 1.0f);
}

// Round 6
// 260.115 us; speedup vs baseline: 1.1996x; 1.1996x over previous
//
#include <hip/hip_runtime.h>
#include <math.h>

// CapsLayer dynamic routing, MI355X fp32.
// x: [64, 2048, 8]  W: [2048, 32, 8, 16]  out: [64, 32, 16]
// Never materialize u_hat (256 MB); recompute per routing pass.
// R8 == R7 resubmitted (R7 bench was an infra failure: "container failed
// twice" — kernel never ran). R5 body + __launch_bounds__(256,8). History:
//   R3: (256,8) w/o unroll guard -> unroller hoisted 64 W loads -> spill.
//   R5: unroll-1 guard + (256,4) -> 36 VGPR, no spill, 47.6us/pass, Occ 45%
//       (= the 4-block floor). Latency-bound: VALUBusy 18%, HBM 18%.
//   R6: register ping-pong ILP -> re-spilled (FETCH 165MB). ILP = spill-bait.
// This round doubles RESIDENCY: unroll-1 guard keeps natural alloc at 36
// VGPR, under the 64-VGPR cap of (256,8) -> 8 blocks/CU = 32 waves/CU, 2x
// latency-hiding for the serial [8 W-loads -> vmcnt -> ~540cyc FMA] iter.
// Tripwire: FETCH must stay ~35 MB; >100 MB means the cap re-spilled.
// Kept: aws elimination via dot linearity, parallel 512-block reduce_squash.

#define B_TOT 64
#define I_TOT 2048
#define D_IN  8
#define NC    32
#define EV    16
#define OD    (NC*EV)      // 512 outputs per b
#define BC    8            // batch rows per block
#define NBC   (B_TOT/BC)   // 8 b-chunks
#define ICH   8            // i's per block
#define NIC   (I_TOT/ICH)  // 256 i-chunks

__device__ __forceinline__ void fma4(float4& acc, float a, const float4& w) {
    acc.x = fmaf(a, w.x, acc.x);
    acc.y = fmaf(a, w.y, acc.y);
    acc.z = fmaf(a, w.z, acc.z);
    acc.w = fmaf(a, w.w, acc.w);
}

// MODE 0: c uniform (iter 0)              -> P partials
// MODE 1: c = softmax_n(u . vin)          -> P partials
//         (iter 2 uses vin = v0+v1: dot is linear, so no logit carry needed)
template <int MODE>
__global__ __launch_bounds__(256, 8)   // 8 blocks/CU; safe ONLY with unroll-1
void route_pass(const float* __restrict__ x, const float* __restrict__ W,
                float* __restrict__ P, const float* __restrict__ vin)
{
    __shared__ __align__(16) float xl[BC * ICH * D_IN];   // 2 KB
    __shared__ float wsum[2][4][BC];                      // 256 B (double-buffered)

    const int t  = threadIdx.x;
    // XCD swizzle: blk%8 == ic%8 (NIC = 256 ≡ 0 mod 8), so the 8 bc-siblings
    // of an ic (which share W[i0..i0+7]) land on the same XCD's L2.
    const int ic = blockIdx.x & (NIC - 1);   // 0..255
    const int bc = blockIdx.x >> 8;          // 0..7
    const int b0 = bc * BC;
    const int i0 = ic * ICH;
    const int eq = t & 3;          // e quarter (4 e's)
    const int bh = (t >> 2) & 1;   // b half (4 b's each)
    const int n  = t >> 3;         // capsule 0..31
    const int w  = t >> 6;         // wave 0..3

    // ---- stage x[b0..b0+7][i0..i0+7][0..7] once (2 KB) ----
    if (t < 128) {
        const int row = t >> 4, f = (t & 15) * 4;
        *(float4*)&xl[row * (ICH * D_IN) + f] =
            *(const float4*)&x[((size_t)(b0 + row) * I_TOT + i0) * D_IN + f];
    }

    // ---- v fragments in registers (loaded once; L2-hot, tiny) ----
    float4 vr[4];
    if (MODE == 1) {
        #pragma unroll
        for (int q = 0; q < 4; ++q)
            vr[q] = *(const float4*)&vin[(size_t)(b0 + bh * 4 + q) * OD + n * EV + eq * 4];
    }
    __syncthreads();

    float4 sacc[4];
    #pragma unroll
    for (int q = 0; q < 4; ++q) sacc[q] = make_float4(0.f, 0.f, 0.f, 0.f);

    const float* Wt = &W[(size_t)i0 * 4096 + n * 128 + eq * 4];

    // unroll 1 is load-bearing: with ICH=8 the unroller otherwise flattens
    // this loop and hoists 64 float4 W loads -> 256 VGPRs -> scratch spill
    // (R3/R4: 1.1 GB/pass HBM, VALUBusy 2.8%). Keep per-iter live set small;
    // latency is hidden by TLP (8 blocks/CU), not ILP (R6: ILP re-spilled).
    #pragma unroll 1
    for (int ii = 0; ii < ICH; ++ii) {
        // ---- this thread's W fragment straight from global (64B-coalesced) ----
        float4 wr[8];
        #pragma unroll
        for (int d = 0; d < 8; ++d)
            wr[d] = *(const float4*)&Wt[ii * 4096 + d * 16];

        // ---- u[bl][eq*4..+3] for 4 batch rows ----
        float4 u[4];
        #pragma unroll
        for (int q = 0; q < 4; ++q) {
            const int bl = bh * 4 + q;
            float4 xa = *(float4*)&xl[bl * (ICH * D_IN) + ii * 8];
            float4 xb = *(float4*)&xl[bl * (ICH * D_IN) + ii * 8 + 4];
            float4 uu = make_float4(0.f, 0.f, 0.f, 0.f);
            fma4(uu, xa.x, wr[0]); fma4(uu, xa.y, wr[1]);
            fma4(uu, xa.z, wr[2]); fma4(uu, xa.w, wr[3]);
            fma4(uu, xb.x, wr[4]); fma4(uu, xb.y, wr[5]);
            fma4(uu, xb.z, wr[6]); fma4(uu, xb.w, wr[7]);
            u[q] = uu;
        }

        if (MODE == 0) {
            #pragma unroll
            for (int q = 0; q < 4; ++q) {
                sacc[q].x += u[q].x; sacc[q].y += u[q].y;
                sacc[q].z += u[q].z; sacc[q].w += u[q].w;
            }
            // no barrier: xl is read-only, no LDS communication
        } else {
            // ---- a[bl] = dot(u, v) over e: 4 in-thread + shfl over eq bits ----
            float a[4];
            #pragma unroll
            for (int q = 0; q < 4; ++q) {
                float ap = u[q].x * vr[q].x + u[q].y * vr[q].y
                         + u[q].z * vr[q].z + u[q].w * vr[q].w;
                ap += __shfl_xor(ap, 1, 64);
                ap += __shfl_xor(ap, 2, 64);
                a[q] = ap;
            }
            // ---- softmax over n: exp, in-wave partial over this wave's 8 n's ----
            float e[4], p[4];
            #pragma unroll
            for (int q = 0; q < 4; ++q) {
                e[q] = __expf(a[q]);
                float pp = e[q];
                pp += __shfl_xor(pp, 8, 64);
                pp += __shfl_xor(pp, 16, 64);
                pp += __shfl_xor(pp, 32, 64);
                p[q] = pp;       // sum over n in this wave, for bl = bh*4+q
            }
            if (eq == 0) {
                #pragma unroll
                for (int q = 0; q < 4; ++q)
                    wsum[ii & 1][w][bh * 4 + q] = p[q];
            }
            __syncthreads();     // the ONLY barrier per i (wsum double-buffered)
            #pragma unroll
            for (int q = 0; q < 4; ++q) {
                const int bl = bh * 4 + q;
                float s = wsum[ii & 1][0][bl] + wsum[ii & 1][1][bl]
                        + wsum[ii & 1][2][bl] + wsum[ii & 1][3][bl];
                float c = e[q] / s;
                fma4(sacc[q], c, u[q]);
            }
        }
    }

    // ---- write partials: P[ic][b][o] (64B-coalesced, full 128B lines/wave) ----
    #pragma unroll
    for (int q = 0; q < 4; ++q)
        *(float4*)&P[((size_t)ic * B_TOT + b0 + bh * 4 + q) * OD + n * EV + eq * 4] = sacc[q];
}

// Reduce partials over 256 i-chunks, then squash per (b, n).
// Grid: 64 b x 8 output-slices = 512 blocks (2/CU, all CUs busy).
// Block: 256 threads = 64 outputs x 4 ic-quarters; LDS combine; 64 survivors
// do the squash (norm over the 16-lane e-group) and store.
// If addsrc != null, out = squash(...) + addsrc  (used to produce v0+v1).
__global__ __launch_bounds__(256, 4)
void reduce_squash(const float* __restrict__ P, float* __restrict__ dst,
                   const float* __restrict__ addsrc, float pre)
{
    __shared__ float red[256];
    const int b   = blockIdx.x >> 3;
    const int oq  = blockIdx.x & 7;
    const int t   = threadIdx.x;
    const int o   = oq * 64 + (t & 63);
    const int icq = t >> 6;                       // 0..3
    const size_t stride = (size_t)B_TOT * OD;     // per-ic stride in floats

    float s = 0.f;
    size_t base = ((size_t)(icq * 64) * B_TOT + b) * OD + o;
    #pragma unroll 8
    for (int k = 0; k < 64; ++k) s += P[base + (size_t)k * stride];
    red[t] = s;
    __syncthreads();

    if (t < 64) {
        float v = red[t] + red[t + 64] + red[t + 128] + red[t + 192];
        v *= pre;
        // squared norm over e (16 consecutive lanes = one capsule)
        float q2 = v * v;
        q2 += __shfl_xor(q2, 1, 64);
        q2 += __shfl_xor(q2, 2, 64);
        q2 += __shfl_xor(q2, 4, 64);
        q2 += __shfl_xor(q2, 8, 64);
        float sc = q2 / ((1.0f + q2) * sqrtf(q2));
        float outv = v * sc;
        if (addsrc) outv += addsrc[b * OD + o];
        dst[b * OD + o] = outv;
    }
}

extern "C" void kernel_launch(void* const* d_in, const int* in_sizes, int n_in,
                              void* d_out, int out_size, void* d_ws, size_t ws_size,
                              hipStream_t stream) {
    const float* x = (const float*)d_in[0];
    const float* W = (const float*)d_in[1];
    float* out = (float*)d_out;

    char* ws = (char*)d_ws;
    float* P  = (float*)ws;                               // NIC*64*512*4 = 32 MB
    float* v0 = (float*)(ws + (size_t)32 * 1024 * 1024);  // 64*512*4 = 128 KB
    float* vs = v0 + B_TOT * OD;                          // v0 + v1

    dim3 rg(NBC * NIC), rb(256);   // 2048 blocks = 8/CU resident at <=64 VGPR
    dim3 sg(B_TOT * 8), sb(256);   // 512 blocks

    // iter 0: uniform c = 1/32
    route_pass<0><<<rg, rb, 0, stream>>>(x, W, P, nullptr);
    reduce_squash<<<sg, sb, 0, stream>>>(P, v0, nullptr, 1.0f / 32.0f);
    // iter 1: c = softmax(u.v0)
    route_pass<1><<<rg, rb, 0, stream>>>(x, W, P, v0);
    // vs = v0 + v1  (iter-2 logits: u.v0 + u.v1 = u.(v0+v1))
    reduce_squash<<<sg, sb, 0, stream>>>(P, vs, v0, 1.0f);
    // iter 2: c = softmax(u.(v0+v1)); final
    route_pass<1><<<rg, rb, 0, stream>>>(x, W, P, vs);
    reduce_squash<<<sg, sb, 0, stream>>>(P, out, nullptr, 1.0f);
}

// Round 7
// 200.472 us; speedup vs baseline: 1.5565x; 1.2975x over previous
//
#include <hip/hip_runtime.h>
#include <math.h>

// CapsLayer dynamic routing, MI355X fp32.
// x: [64, 2048, 8]  W: [2048, 32, 8, 16]  out: [64, 32, 16]
// Never materialize u_hat (256 MB); recompute per routing pass.
// R9: W via global_load_lds double-buffer. Register-file history:
//   R3/R8: (256,8) 64-VGPR cap -> allocator squeezes to 32 + scratch spill
//          (FETCH 170-800 MB). R6: register ping-pong ILP -> same. R5 (best,
//          47.6us/pass): 36 VGPR clean but allocator splits the 8-float4 W
//          batch -> ~1450 cyc of serial HBM latency per ii, VALUBusy 18%.
// Fix: W never touches VGPRs on the load path. Per ii, each wave stages its
// own 4 KB of the 16 KB W[i] tile into LDS with 4x global_load_lds width=16
// (zero VGPR dest), double-buffered, counted s_waitcnt vmcnt(4) so the
// prefetch stays in flight a full iteration (T4). Fragments then come from
// ds_read_b128 (~12 cyc). Wave w stages exactly rows n in [8w,8w+8) = the
// rows its threads (n=t>>3) read -> buffers are wave-private: MODE0 has ZERO
// loop barriers, MODE1 keeps only the lgkm-only wsum barrier.
// Bank conflicts: slot = d ^ (n&7) XOR swizzle, applied by permuting the
// per-lane GLOBAL source address (LDS dest must stay linear - rule #21);
// read side applies the same XOR -> conflict floor.
// Tripwires: FETCH must stay ~35 MB (>100 MB = spill); absmax <= 1e-3.
// Kept: unroll-1 guard, aws elimination via dot linearity, 512-block reduce.

#define B_TOT 64
#define I_TOT 2048
#define D_IN  8
#define NC    32
#define EV    16
#define OD    (NC*EV)      // 512 outputs per b
#define BC    8            // batch rows per block
#define NBC   (B_TOT/BC)   // 8 b-chunks
#define ICH   8            // i's per block
#define NIC   (I_TOT/ICH)  // 256 i-chunks

__device__ __forceinline__ void fma4(float4& acc, float a, const float4& w) {
    acc.x = fmaf(a, w.x, acc.x);
    acc.y = fmaf(a, w.y, acc.y);
    acc.z = fmaf(a, w.z, acc.z);
    acc.w = fmaf(a, w.w, acc.w);
}

// async global->LDS, 16 B per lane. LDS dest must be wave-uniform base
// (HW adds lane*16); global src is per-lane.
__device__ __forceinline__ void gload_lds16(const float* g, float* l) {
    __builtin_amdgcn_global_load_lds(
        (const __attribute__((address_space(1))) unsigned int*)g,
        (__attribute__((address_space(3))) unsigned int*)l,
        16, 0, 0);
}

// MODE 0: c uniform (iter 0)              -> P partials
// MODE 1: c = softmax_n(u . vin)          -> P partials
//         (iter 2 uses vin = v0+v1: dot is linear, so no logit carry needed)
template <int MODE>
__global__ __launch_bounds__(256, 4)
void route_pass(const float* __restrict__ x, const float* __restrict__ W,
                float* __restrict__ P, const float* __restrict__ vin)
{
    // W[i] tile = 32 caps x 8 d x 16 e fp32 = 16 KB; double-buffered.
    // Element W[n][d][e] lives at dword n*128 + (d^(n&7))*16 + e  (swizzled).
    __shared__ __align__(16) float wbuf[2][4096];         // 32 KB
    __shared__ __align__(16) float xl[BC * ICH * D_IN];   // 2 KB
    __shared__ float wsum[2][4][BC];                      // 256 B (dbuf)

    const int t  = threadIdx.x;
    // XCD swizzle: blk%8 == ic%8 (NIC = 256 ≡ 0 mod 8), so the 8 bc-siblings
    // of an ic (which share W[i0..i0+7]) land on the same XCD's L2.
    const int ic = blockIdx.x & (NIC - 1);   // 0..255
    const int bc = blockIdx.x >> 8;          // 0..7
    const int b0 = bc * BC;
    const int i0 = ic * ICH;
    const int eq = t & 3;          // e quarter (4 e's)
    const int bh = (t >> 2) & 1;   // b half (4 b's each)
    const int n  = t >> 3;         // capsule 0..31
    const int w  = t >> 6;         // wave 0..3
    const int lane = t & 63;

    // ---- staging decode (loop-invariant): wave w, issue j, lane l writes
    // LDS dword D = w*1024 + j*256 + l*4. Decode D -> (ns, slot, eqs), then
    // the element that belongs there is W dword ns*128 + (slot^(ns&7))*16
    // + eqs*4 (inverse of the read-side XOR; XOR is an involution).
    int soff[4];
    #pragma unroll
    for (int j = 0; j < 4; ++j) {
        const int ns   = w * 8 + j * 2 + (lane >> 5);
        const int slot = (lane >> 2) & 7;
        const int eqs  = lane & 3;
        const int d    = slot ^ (ns & 7);
        soff[j] = ns * 128 + d * 16 + eqs * 4;   // dword offset in W[i] tile
    }
    const float* Wic = W + (size_t)i0 * 4096;    // 4096 floats per i
    const int wdst = w * 1024;                   // wave's float offset in wbuf

    // ---- prologue: stage tile 0 into wbuf[0] (async, drained by syncthreads)
    #pragma unroll
    for (int j = 0; j < 4; ++j)
        gload_lds16(Wic + soff[j], &wbuf[0][wdst + j * 256]);

    // ---- stage x[b0..b0+7][i0..i0+7][0..7] once (2 KB) ----
    if (t < 128) {
        const int row = t >> 4, f = (t & 15) * 4;
        *(float4*)&xl[row * (ICH * D_IN) + f] =
            *(const float4*)&x[((size_t)(b0 + row) * I_TOT + i0) * D_IN + f];
    }

    // ---- v fragments in registers (loaded once; L2-hot, tiny) ----
    float4 vr[4];
    if (MODE == 1) {
        #pragma unroll
        for (int q = 0; q < 4; ++q)
            vr[q] = *(const float4*)&vin[(size_t)(b0 + bh * 4 + q) * OD + n * EV + eq * 4];
    }
    __syncthreads();   // xl visible to all waves; also drains prologue stage

    float4 sacc[4];
    #pragma unroll
    for (int q = 0; q < 4; ++q) sacc[q] = make_float4(0.f, 0.f, 0.f, 0.f);

    const int nx = n & 7;
    const int rbase = n * 128 + eq * 4;   // dword base of this thread's row

    // unroll 1 is load-bearing: full unroll re-creates the R3/R4 hoist-spill.
    #pragma unroll 1
    for (int ii = 0; ii < ICH; ++ii) {
        const int cur = ii & 1;
        if (ii + 1 < ICH) {
            // issue next tile's stage (async, zero VGPR dest), then counted
            // wait: vmcnt(4) = "the 4 just-issued may remain" = tile ii done.
            const float* ws = Wic + (size_t)(ii + 1) * 4096;
            #pragma unroll
            for (int j = 0; j < 4; ++j)
                gload_lds16(ws + soff[j], &wbuf[cur ^ 1][wdst + j * 256]);
            asm volatile("s_waitcnt vmcnt(4)" ::: "memory");
        } else {
            asm volatile("s_waitcnt vmcnt(0)" ::: "memory");
        }

        // ---- W fragments from LDS (swizzled: bank-conflict floor) ----
        float4 wr[8];
        #pragma unroll
        for (int d = 0; d < 8; ++d)
            wr[d] = *(const float4*)&wbuf[cur][rbase + ((d ^ nx) << 4)];

        // ---- u[bl][eq*4..+3] for 4 batch rows ----
        float4 u[4];
        #pragma unroll
        for (int q = 0; q < 4; ++q) {
            const int bl = bh * 4 + q;
            float4 xa = *(float4*)&xl[bl * (ICH * D_IN) + ii * 8];
            float4 xb = *(float4*)&xl[bl * (ICH * D_IN) + ii * 8 + 4];
            float4 uu = make_float4(0.f, 0.f, 0.f, 0.f);
            fma4(uu, xa.x, wr[0]); fma4(uu, xa.y, wr[1]);
            fma4(uu, xa.z, wr[2]); fma4(uu, xa.w, wr[3]);
            fma4(uu, xb.x, wr[4]); fma4(uu, xb.y, wr[5]);
            fma4(uu, xb.z, wr[6]); fma4(uu, xb.w, wr[7]);
            u[q] = uu;
        }

        if (MODE == 0) {
            #pragma unroll
            for (int q = 0; q < 4; ++q) {
                sacc[q].x += u[q].x; sacc[q].y += u[q].y;
                sacc[q].z += u[q].z; sacc[q].w += u[q].w;
            }
            // ZERO barriers: wave w stages & reads only rows [8w,8w+8) ->
            // wbuf double-buffer hazards are wave-private (program order).
        } else {
            // ---- a[bl] = dot(u, v) over e: 4 in-thread + shfl over eq bits ----
            float a[4];
            #pragma unroll
            for (int q = 0; q < 4; ++q) {
                float ap = u[q].x * vr[q].x + u[q].y * vr[q].y
                         + u[q].z * vr[q].z + u[q].w * vr[q].w;
                ap += __shfl_xor(ap, 1, 64);
                ap += __shfl_xor(ap, 2, 64);
                a[q] = ap;
            }
            // ---- softmax over n: exp, in-wave partial over this wave's 8 n's ----
            float e[4], p[4];
            #pragma unroll
            for (int q = 0; q < 4; ++q) {
                e[q] = __expf(a[q]);
                float pp = e[q];
                pp += __shfl_xor(pp, 8, 64);
                pp += __shfl_xor(pp, 16, 64);
                pp += __shfl_xor(pp, 32, 64);
                p[q] = pp;       // sum over n in this wave, for bl = bh*4+q
            }
            if (eq == 0) {
                #pragma unroll
                for (int q = 0; q < 4; ++q)
                    wsum[cur][w][bh * 4 + q] = p[q];
            }
            // lgkm-only barrier (R6-proven): protects wsum without draining
            // vmcnt -> the just-issued stage stays in flight across it.
            asm volatile("s_waitcnt lgkmcnt(0)\n\ts_barrier" ::: "memory");
            #pragma unroll
            for (int q = 0; q < 4; ++q) {
                const int bl = bh * 4 + q;
                float s = wsum[cur][0][bl] + wsum[cur][1][bl]
                        + wsum[cur][2][bl] + wsum[cur][3][bl];
                float c = e[q] / s;
                fma4(sacc[q], c, u[q]);
            }
        }
    }

    // ---- write partials: P[ic][b][o] (64B-coalesced, full 128B lines/wave) ----
    #pragma unroll
    for (int q = 0; q < 4; ++q)
        *(float4*)&P[((size_t)ic * B_TOT + b0 + bh * 4 + q) * OD + n * EV + eq * 4] = sacc[q];
}

// Reduce partials over 256 i-chunks, then squash per (b, n).
// Grid: 64 b x 8 output-slices = 512 blocks (2/CU, all CUs busy).
// Block: 256 threads = 64 outputs x 4 ic-quarters; LDS combine; 64 survivors
// do the squash (norm over the 16-lane e-group) and store.
// If addsrc != null, out = squash(...) + addsrc  (used to produce v0+v1).
__global__ __launch_bounds__(256, 4)
void reduce_squash(const float* __restrict__ P, float* __restrict__ dst,
                   const float* __restrict__ addsrc, float pre)
{
    __shared__ float red[256];
    const int b   = blockIdx.x >> 3;
    const int oq  = blockIdx.x & 7;
    const int t   = threadIdx.x;
    const int o   = oq * 64 + (t & 63);
    const int icq = t >> 6;                       // 0..3
    const size_t stride = (size_t)B_TOT * OD;     // per-ic stride in floats

    float s = 0.f;
    size_t base = ((size_t)(icq * 64) * B_TOT + b) * OD + o;
    #pragma unroll 8
    for (int k = 0; k < 64; ++k) s += P[base + (size_t)k * stride];
    red[t] = s;
    __syncthreads();

    if (t < 64) {
        float v = red[t] + red[t + 64] + red[t + 128] + red[t + 192];
        v *= pre;
        // squared norm over e (16 consecutive lanes = one capsule)
        float q2 = v * v;
        q2 += __shfl_xor(q2, 1, 64);
        q2 += __shfl_xor(q2, 2, 64);
        q2 += __shfl_xor(q2, 4, 64);
        q2 += __shfl_xor(q2, 8, 64);
        float sc = q2 / ((1.0f + q2) * sqrtf(q2));
        float outv = v * sc;
        if (addsrc) outv += addsrc[b * OD + o];
        dst[b * OD + o] = outv;
    }
}

extern "C" void kernel_launch(void* const* d_in, const int* in_sizes, int n_in,
                              void* d_out, int out_size, void* d_ws, size_t ws_size,
                              hipStream_t stream) {
    const float* x = (const float*)d_in[0];
    const float* W = (const float*)d_in[1];
    float* out = (float*)d_out;

    char* ws = (char*)d_ws;
    float* P  = (float*)ws;                               // NIC*64*512*4 = 32 MB
    float* v0 = (float*)(ws + (size_t)32 * 1024 * 1024);  // 64*512*4 = 128 KB
    float* vs = v0 + B_TOT * OD;                          // v0 + v1

    dim3 rg(NBC * NIC), rb(256);   // 2048 blocks; 4/CU (LDS-capped, 34.5 KB)
    dim3 sg(B_TOT * 8), sb(256);   // 512 blocks

    // iter 0: uniform c = 1/32
    route_pass<0><<<rg, rb, 0, stream>>>(x, W, P, nullptr);
    reduce_squash<<<sg, sb, 0, stream>>>(P, v0, nullptr, 1.0f / 32.0f);
    // iter 1: c = softmax(u.v0)
    route_pass<1><<<rg, rb, 0, stream>>>(x, W, P, v0);
    // vs = v0 + v1  (iter-2 logits: u.v0 + u.v1 = u.(v0+v1))
    reduce_squash<<<sg, sb, 0, stream>>>(P, vs, v0, 1.0f);
    // iter 2: c = softmax(u.(v0+v1)); final
    route_pass<1><<<rg, rb, 0, stream>>>(x, W, P, vs);
    reduce_squash<<<sg, sb, 0, stream>>>(P, out, nullptr, 1.0f);
}